// Round 1
// baseline (794.167 us; speedup 1.0000x reference)
//
#include <hip/hip_runtime.h>
#include <hip/hip_bf16.h>

#define BATCH 8
#define NN 4096
#define EE 1024
#define DIN 256
#define DOUT 256
#define EPS 1e-8f

// ---------------- degree kernels ----------------

// one wave per row of H: d_v_inv_sqrt[b,n] = rsqrt(max(sum_e H[b,n,e], EPS))
__global__ __launch_bounds__(256) void dv_kernel(const float* __restrict__ H,
                                                 float* __restrict__ dv_is) {
    int row = blockIdx.x * 4 + (threadIdx.x >> 6);   // [0, BATCH*NN)
    int lane = threadIdx.x & 63;
    const float4* p = (const float4*)(H + (size_t)row * EE);
    float s = 0.f;
#pragma unroll
    for (int j = 0; j < 4; ++j) {
        float4 v = p[j * 64 + lane];
        s += v.x + v.y + v.z + v.w;
    }
#pragma unroll
    for (int off = 32; off; off >>= 1) s += __shfl_down(s, off);
    if (lane == 0) dv_is[row] = rsqrtf(fmaxf(s, EPS));
}

__global__ void zero_kernel(float* __restrict__ p, int n) {
    int i = blockIdx.x * 256 + threadIdx.x;
    if (i < n) p[i] = 0.f;
}

// column sums of H with per-chunk atomics: de_acc[b,e] += sum_{n in chunk} H[b,n,e]
__global__ __launch_bounds__(256) void de_kernel(const float* __restrict__ H,
                                                 float* __restrict__ de_acc) {
    int b = blockIdx.x >> 4, chunk = blockIdx.x & 15;     // 16 chunks of 256 rows
    int e = blockIdx.y * 256 + threadIdx.x;
    const float* p = H + ((size_t)b * NN + chunk * 256) * EE + e;
    float s = 0.f;
    for (int n = 0; n < 256; ++n) s += p[(size_t)n * EE];
    atomicAdd(&de_acc[b * EE + e], s);
}

__global__ void de_finalize(float* __restrict__ de) {
    int i = blockIdx.x * 256 + threadIdx.x;
    de[i] = 1.0f / fmaxf(de[i], EPS);
}

// ---------------- GEMM kernels (64x64 tile, 256 thr, 4x4 micro-tile) ----------------

// T[b,m,f] = dv_is[b,m] * sum_k X[b,m,k] * W[k,f]
__global__ __launch_bounds__(256) void gemm_xw(const float* __restrict__ X,
                                               const float* __restrict__ W,
                                               const float* __restrict__ dv_is,
                                               float* __restrict__ T) {
    int b = blockIdx.z;
    int m0 = blockIdx.x * 64, f0 = blockIdx.y * 64;
    const float* A = X + (size_t)b * NN * DIN;
    __shared__ float As[16][68];
    __shared__ float Bs[16][68];
    int tid = threadIdx.x;
    int ar = tid >> 2, ac = (tid & 3) << 2;     // A: row m0+ar, k = k0+ac..+3 (transpose store)
    int br = tid >> 4, bc = (tid & 15) << 2;    // B: row k0+br, col f0+bc (direct store)
    int r0 = (tid >> 4) << 2, c0 = (tid & 15) << 2;
    float acc[4][4] = {};
    for (int k0 = 0; k0 < DIN; k0 += 16) {
        float4 av = *(const float4*)&A[(size_t)(m0 + ar) * DIN + k0 + ac];
        float4 bv = *(const float4*)&W[(size_t)(k0 + br) * DOUT + f0 + bc];
        __syncthreads();
        As[ac + 0][ar] = av.x; As[ac + 1][ar] = av.y;
        As[ac + 2][ar] = av.z; As[ac + 3][ar] = av.w;
        *(float4*)&Bs[br][bc] = bv;
        __syncthreads();
#pragma unroll
        for (int k = 0; k < 16; ++k) {
            float4 a4 = *(const float4*)&As[k][r0];
            float4 b4 = *(const float4*)&Bs[k][c0];
            float a[4] = {a4.x, a4.y, a4.z, a4.w};
            float bb[4] = {b4.x, b4.y, b4.z, b4.w};
#pragma unroll
            for (int i = 0; i < 4; ++i)
#pragma unroll
                for (int j = 0; j < 4; ++j) acc[i][j] = fmaf(a[i], bb[j], acc[i][j]);
        }
    }
#pragma unroll
    for (int i = 0; i < 4; ++i) {
        float dv = dv_is[b * NN + m0 + r0 + i];
        float4 o = {dv * acc[i][0], dv * acc[i][1], dv * acc[i][2], dv * acc[i][3]};
        *(float4*)&T[((size_t)b * NN + m0 + r0 + i) * DOUT + f0 + c0] = o;
    }
}

// U[b,e,f] = de_inv[b,e] * sum_n H[b,n,e] * T[b,n,f]
__global__ __launch_bounds__(256) void gemm_ht(const float* __restrict__ H,
                                               const float* __restrict__ T,
                                               const float* __restrict__ de_inv,
                                               float* __restrict__ U) {
    int b = blockIdx.z;
    int e0 = blockIdx.x * 64, f0 = blockIdx.y * 64;
    const float* Hb = H + (size_t)b * NN * EE;
    const float* Tb = T + (size_t)b * NN * DOUT;
    __shared__ float As[16][68];
    __shared__ float Bs[16][68];
    int tid = threadIdx.x;
    int lr = tid >> 4, lc = (tid & 15) << 2;    // both loads direct: [n-local][col]
    int r0 = (tid >> 4) << 2, c0 = (tid & 15) << 2;
    float acc[4][4] = {};
    for (int n0 = 0; n0 < NN; n0 += 16) {
        float4 av = *(const float4*)&Hb[(size_t)(n0 + lr) * EE + e0 + lc];
        float4 bv = *(const float4*)&Tb[(size_t)(n0 + lr) * DOUT + f0 + lc];
        __syncthreads();
        *(float4*)&As[lr][lc] = av;
        *(float4*)&Bs[lr][lc] = bv;
        __syncthreads();
#pragma unroll
        for (int k = 0; k < 16; ++k) {
            float4 a4 = *(const float4*)&As[k][r0];
            float4 b4 = *(const float4*)&Bs[k][c0];
            float a[4] = {a4.x, a4.y, a4.z, a4.w};
            float bb[4] = {b4.x, b4.y, b4.z, b4.w};
#pragma unroll
            for (int i = 0; i < 4; ++i)
#pragma unroll
                for (int j = 0; j < 4; ++j) acc[i][j] = fmaf(a[i], bb[j], acc[i][j]);
        }
    }
#pragma unroll
    for (int i = 0; i < 4; ++i) {
        float de = de_inv[b * EE + e0 + r0 + i];
        float4 o = {de * acc[i][0], de * acc[i][1], de * acc[i][2], de * acc[i][3]};
        *(float4*)&U[((size_t)b * EE + e0 + r0 + i) * DOUT + f0 + c0] = o;
    }
}

// out[b,n,f] = dv_is[b,n] * sum_e H[b,n,e] * U[b,e,f] + bias[f]
__global__ __launch_bounds__(256) void gemm_hu(const float* __restrict__ H,
                                               const float* __restrict__ U,
                                               const float* __restrict__ dv_is,
                                               const float* __restrict__ bias,
                                               float* __restrict__ out) {
    int b = blockIdx.z;
    int n0 = blockIdx.x * 64, f0 = blockIdx.y * 64;
    const float* Hb = H + (size_t)b * NN * EE;
    const float* Ub = U + (size_t)b * EE * DOUT;
    __shared__ float As[16][68];
    __shared__ float Bs[16][68];
    int tid = threadIdx.x;
    int ar = tid >> 2, ac = (tid & 3) << 2;     // A: row n0+ar, k = k0+ac..+3 (transpose store)
    int br = tid >> 4, bc = (tid & 15) << 2;    // B: row k0+br, col f0+bc (direct store)
    int r0 = (tid >> 4) << 2, c0 = (tid & 15) << 2;
    float acc[4][4] = {};
    for (int k0 = 0; k0 < EE; k0 += 16) {
        float4 av = *(const float4*)&Hb[(size_t)(n0 + ar) * EE + k0 + ac];
        float4 bv = *(const float4*)&Ub[(size_t)(k0 + br) * DOUT + f0 + bc];
        __syncthreads();
        As[ac + 0][ar] = av.x; As[ac + 1][ar] = av.y;
        As[ac + 2][ar] = av.z; As[ac + 3][ar] = av.w;
        *(float4*)&Bs[br][bc] = bv;
        __syncthreads();
#pragma unroll
        for (int k = 0; k < 16; ++k) {
            float4 a4 = *(const float4*)&As[k][r0];
            float4 b4 = *(const float4*)&Bs[k][c0];
            float a[4] = {a4.x, a4.y, a4.z, a4.w};
            float bb[4] = {b4.x, b4.y, b4.z, b4.w};
#pragma unroll
            for (int i = 0; i < 4; ++i)
#pragma unroll
                for (int j = 0; j < 4; ++j) acc[i][j] = fmaf(a[i], bb[j], acc[i][j]);
        }
    }
    float4 bi = *(const float4*)&bias[f0 + c0];
#pragma unroll
    for (int i = 0; i < 4; ++i) {
        float dv = dv_is[b * NN + n0 + r0 + i];
        float4 o = {dv * acc[i][0] + bi.x, dv * acc[i][1] + bi.y,
                    dv * acc[i][2] + bi.z, dv * acc[i][3] + bi.w};
        *(float4*)&out[((size_t)b * NN + n0 + r0 + i) * DOUT + f0 + c0] = o;
    }
}

extern "C" void kernel_launch(void* const* d_in, const int* in_sizes, int n_in,
                              void* d_out, int out_size, void* d_ws, size_t ws_size,
                              hipStream_t stream) {
    const float* x    = (const float*)d_in[0];   // [B,N,DIN]
    const float* H    = (const float*)d_in[1];   // [B,N,E]
    const float* W    = (const float*)d_in[2];   // [DIN,DOUT]
    const float* bias = (const float*)d_in[3];   // [DOUT]
    float* out = (float*)d_out;                  // [B,N,DOUT]

    // workspace layout (floats): dv_is [B*N], de [B*E], U [B*E*DOUT]
    float* ws = (float*)d_ws;
    float* dv_is = ws;                       // 32768
    float* de    = ws + BATCH * NN;          // 8192
    float* U     = de + BATCH * EE;          // 2097152
    // T aliases d_out (exactly [B,N,DOUT]); consumed by gemm_ht before gemm_hu overwrites.
    float* T = out;

    // degrees
    dv_kernel<<<BATCH * NN / 4, 256, 0, stream>>>(H, dv_is);
    zero_kernel<<<(BATCH * EE + 255) / 256, 256, 0, stream>>>(de, BATCH * EE);
    de_kernel<<<dim3(BATCH * 16, EE / 256), 256, 0, stream>>>(H, de);
    de_finalize<<<BATCH * EE / 256, 256, 0, stream>>>(de);

    // T = Dv^{-1/2} (X W)        [B,N,DOUT]
    gemm_xw<<<dim3(NN / 64, DOUT / 64, BATCH), 256, 0, stream>>>(x, W, dv_is, T);
    // U = De^{-1} (H^T T)        [B,E,DOUT]
    gemm_ht<<<dim3(EE / 64, DOUT / 64, BATCH), 256, 0, stream>>>(H, T, de, U);
    // out = Dv^{-1/2} (H U) + b  [B,N,DOUT]
    gemm_hu<<<dim3(NN / 64, DOUT / 64, BATCH), 256, 0, stream>>>(H, U, dv_is, bias, out);
}

// Round 2
// 351.637 us; speedup vs baseline: 2.2585x; 2.2585x over previous
//
#include <hip/hip_runtime.h>
#include <hip/hip_bf16.h>

#define BATCH 8
#define NN 4096
#define EE 1024
#define DIN 256
#define DOUT 256
#define EPS 1e-8f

typedef short bf16x8 __attribute__((ext_vector_type(8)));
typedef float f32x4 __attribute__((ext_vector_type(4)));

__device__ __forceinline__ unsigned short f2bf(float f) {
    unsigned u = __float_as_uint(f);
    return (unsigned short)((u + 0x7FFFu + ((u >> 16) & 1u)) >> 16);  // RNE, no NaN inputs
}

__device__ __forceinline__ void g2l16(const void* g, void* l) {
    __builtin_amdgcn_global_load_lds(
        (const __attribute__((address_space(1))) unsigned*)g,
        (__attribute__((address_space(3))) unsigned*)l, 16, 0, 0);
}

// ---- shared 128x128x(BK=32) TN GEMM core: C[i][j] = sum_k A'[i][k] * B'[j][k] ----
// LDS tile: row r (128) x 4 chunks of 8 bf16; chunk slot swizzled: hh = c ^ ((r>>1)&3)
// -> fragment ds_read_b128 spreads over all 8 bank positions (2-way aliasing = free).

template <int LD>
__device__ __forceinline__ void stage_tile(const unsigned short* src, int k0, short* lds, int tid) {
#pragma unroll
    for (int j = 0; j < 2; ++j) {
        int q = tid + j * 256;            // 512 chunks of 16B = 8KB tile
        int r = q >> 2;
        int c = (q ^ (r >> 1)) & 3;       // global k-chunk for this LDS slot
        g2l16(src + (size_t)r * LD + k0 + c * 8, (char*)lds + q * 16);
    }
}

__device__ __forceinline__ bf16x8 frag_ld(const short* lds, int r, int c) {
    int off = (r << 6) | (((c ^ (r >> 1)) & 3) << 4);
    return *(const bf16x8*)((const char*)lds + off);
}

template <int LDA, int LDB>
__device__ __forceinline__ void gemm_core(const unsigned short* A, const unsigned short* B,
                                          int kIters, int k0, f32x4 acc[4][4],
                                          short* As, short* Bs) {
    int tid = threadIdx.x, lane = tid & 63, wave = tid >> 6;
    int wm = (wave >> 1) * 64, wn = (wave & 1) * 64;
    int fr = lane & 15, fc = lane >> 4;
    for (int kt = 0; kt < kIters; ++kt) {
        int k = k0 + kt * 32;
        __syncthreads();
        stage_tile<LDA>(A, k, As, tid);
        stage_tile<LDB>(B, k, Bs, tid);
        __syncthreads();                 // drains vmcnt -> LDS data ready
        bf16x8 av[4], bv[4];
#pragma unroll
        for (int i = 0; i < 4; ++i) av[i] = frag_ld(As, wm + i * 16 + fr, fc);
#pragma unroll
        for (int j = 0; j < 4; ++j) bv[j] = frag_ld(Bs, wn + j * 16 + fr, fc);
#pragma unroll
        for (int i = 0; i < 4; ++i)
#pragma unroll
            for (int j = 0; j < 4; ++j)
                acc[i][j] = __builtin_amdgcn_mfma_f32_16x16x32_bf16(av[i], bv[j], acc[i][j], 0, 0, 0);
    }
}

// ---------------- prep kernels ----------------

// H fp32 -> H_bf [b][n][e], Ht_bf [b][e][n]; dv row-sums, de col-sums (atomics)
__global__ __launch_bounds__(256) void prep_h(const float* __restrict__ H,
                                              unsigned short* __restrict__ Hb,
                                              unsigned short* __restrict__ Ht,
                                              float* __restrict__ dv_acc,
                                              float* __restrict__ de_acc) {
    __shared__ float tile[64][65];
    int bid = blockIdx.x;                 // 8 * 64 * 16 = 8192
    int b = bid >> 10;
    int nt = (bid >> 4) & 63, et = bid & 15;
    int n0 = nt * 64, e0 = et * 64;
    int t = threadIdx.x;
    int r = t >> 2, cq = (t & 3) * 16;
    const float* src = H + ((size_t)(b * NN + n0 + r)) * EE + e0 + cq;
    float v[16];
    float rs = 0.f;
#pragma unroll
    for (int j = 0; j < 16; j += 4) {
        float4 x4 = *(const float4*)(src + j);
        v[j] = x4.x; v[j + 1] = x4.y; v[j + 2] = x4.z; v[j + 3] = x4.w;
        rs += x4.x + x4.y + x4.z + x4.w;
    }
    // H_bf: row-major direct (32B per thread)
    bf16x8 p0, p1;
#pragma unroll
    for (int j = 0; j < 8; ++j) { p0[j] = (short)f2bf(v[j]); p1[j] = (short)f2bf(v[8 + j]); }
    unsigned short* hd = Hb + ((size_t)(b * NN + n0 + r)) * EE + e0 + cq;
    *(bf16x8*)hd = p0; *(bf16x8*)(hd + 8) = p1;
    // dv partial: 4 consecutive lanes share a row
    rs += __shfl_down(rs, 2);
    rs += __shfl_down(rs, 1);
    if ((t & 3) == 0) atomicAdd(dv_acc + b * NN + n0 + r, rs);
    // transpose via LDS
#pragma unroll
    for (int j = 0; j < 16; ++j) tile[r][cq + j] = v[j];
    __syncthreads();
    int c = t >> 2, rq = (t & 3) * 16;
    float cs = 0.f;
    bf16x8 q0, q1;
#pragma unroll
    for (int j = 0; j < 16; ++j) {
        float x = tile[rq + j][c];
        cs += x;
        if (j < 8) q0[j] = (short)f2bf(x); else q1[j - 8] = (short)f2bf(x);
    }
    cs += __shfl_down(cs, 2);
    cs += __shfl_down(cs, 1);
    if ((t & 3) == 0) atomicAdd(de_acc + b * EE + e0 + c, cs);
    unsigned short* td = Ht + ((size_t)(b * EE + e0 + c)) * NN + n0 + rq;
    *(bf16x8*)td = q0; *(bf16x8*)(td + 8) = q1;
}

// X fp32 -> bf16 (blocks 0..2047); W -> W^T bf16 (blocks 2048..2063)
__global__ __launch_bounds__(256) void prep_xw(const float* __restrict__ X,
                                               const float* __restrict__ W,
                                               unsigned short* __restrict__ Xb,
                                               unsigned short* __restrict__ Wt) {
    __shared__ float tile[64][65];
    int bid = blockIdx.x;
    int t = threadIdx.x;
    if (bid < 2048) {
        size_t base = ((size_t)bid * 256 + t) * 16;
        bf16x8 p0, p1;
#pragma unroll
        for (int j = 0; j < 16; j += 4) {
            float4 x4 = *(const float4*)(X + base + j);
            unsigned short a = f2bf(x4.x), b2 = f2bf(x4.y), c2 = f2bf(x4.z), d2 = f2bf(x4.w);
            if (j < 8) { p0[j] = (short)a; p0[j+1] = (short)b2; p0[j+2] = (short)c2; p0[j+3] = (short)d2; }
            else       { p1[j-8] = (short)a; p1[j-7] = (short)b2; p1[j-6] = (short)c2; p1[j-5] = (short)d2; }
        }
        *(bf16x8*)(Xb + base) = p0; *(bf16x8*)(Xb + base + 8) = p1;
    } else {
        int w = bid - 2048;
        int k0 = (w >> 2) * 64, f0 = (w & 3) * 64;
        int r = t >> 2, cq = (t & 3) * 16;
#pragma unroll
        for (int j = 0; j < 16; j += 4) {
            float4 x4 = *(const float4*)(W + (size_t)(k0 + r) * DOUT + f0 + cq + j);
            tile[r][cq + j] = x4.x; tile[r][cq + j + 1] = x4.y;
            tile[r][cq + j + 2] = x4.z; tile[r][cq + j + 3] = x4.w;
        }
        __syncthreads();
        int c = t >> 2, rq = (t & 3) * 16;
        bf16x8 q0, q1;
#pragma unroll
        for (int j = 0; j < 16; ++j) {
            float x = tile[rq + j][c];
            if (j < 8) q0[j] = (short)f2bf(x); else q1[j - 8] = (short)f2bf(x);
        }
        unsigned short* dst = Wt + (size_t)(f0 + c) * DIN + k0 + rq;
        *(bf16x8*)dst = q0; *(bf16x8*)(dst + 8) = q1;
    }
}

// ---------------- MFMA GEMMs ----------------

// Tt[b][f][n] = rsqrt(max(dv,eps))[m] * sum_k X[m][k] W^T[f][k]
__global__ __launch_bounds__(256) void mfma_xw(const unsigned short* __restrict__ Xb,
                                               const unsigned short* __restrict__ Wt,
                                               const float* __restrict__ dv_acc,
                                               unsigned short* __restrict__ Tt) {
    __shared__ short As[128 * 32], Bs[128 * 32];
    int m0 = blockIdx.x * 128, f0 = blockIdx.y * 128;
    f32x4 acc[4][4] = {};
    gemm_core<DIN, DIN>(Xb + (size_t)m0 * DIN, Wt + (size_t)f0 * DIN, DIN / 32, 0, acc, As, Bs);
    int lane = threadIdx.x & 63, wave = threadIdx.x >> 6;
    int wm = (wave >> 1) * 64, wn = (wave & 1) * 64;
    int rg = (lane >> 4) * 4, cl = lane & 15;
    int b = m0 >> 12, nb = m0 & (NN - 1);
#pragma unroll
    for (int i = 0; i < 4; ++i) {
        int rbase = wm + i * 16 + rg;                    // tile-local row m
        float4 dv = *(const float4*)(dv_acc + m0 + rbase);
        float s0 = rsqrtf(fmaxf(dv.x, EPS)), s1 = rsqrtf(fmaxf(dv.y, EPS));
        float s2 = rsqrtf(fmaxf(dv.z, EPS)), s3 = rsqrtf(fmaxf(dv.w, EPS));
#pragma unroll
        for (int j = 0; j < 4; ++j) {
            int f = f0 + wn + j * 16 + cl;
            f32x4 a = acc[i][j];
            ushort4 o = { f2bf(a.x * s0), f2bf(a.y * s1), f2bf(a.z * s2), f2bf(a.w * s3) };
            *(ushort4*)(Tt + (((size_t)b * DOUT + f) << 12) + nb + rbase) = o;
        }
    }
}

// P[s][b][f][e] = partial_k sum_n Ht[e][n] Tt[f][n]   (split-K = 4)
__global__ __launch_bounds__(256) void mfma_ht(const unsigned short* __restrict__ Ht,
                                               const unsigned short* __restrict__ Tt,
                                               float* __restrict__ P) {
    __shared__ short As[128 * 32], Bs[128 * 32];
    int e0 = blockIdx.x * 128, f0 = blockIdx.y * 128;
    int b = blockIdx.z >> 2, s = blockIdx.z & 3;
    f32x4 acc[4][4] = {};
    gemm_core<NN, NN>(Ht + ((size_t)b * EE + e0) * NN, Tt + ((size_t)b * DOUT + f0) * NN,
                      1024 / 32, s * 1024, acc, As, Bs);
    int lane = threadIdx.x & 63, wave = threadIdx.x >> 6;
    int wm = (wave >> 1) * 64, wn = (wave & 1) * 64;
    int rg = (lane >> 4) * 4, cl = lane & 15;
    float* Pb = P + (size_t)s * (BATCH * DOUT * EE) + (size_t)b * (DOUT * EE);
#pragma unroll
    for (int i = 0; i < 4; ++i) {
        int e = e0 + wm + i * 16 + rg;
#pragma unroll
        for (int j = 0; j < 4; ++j) {
            int f = f0 + wn + j * 16 + cl;
            *(f32x4*)(Pb + (size_t)f * EE + e) = acc[i][j];
        }
    }
}

// Ut[b][f][e] = bf16( (sum_s P) / max(de[b][e], eps) )
__global__ __launch_bounds__(256) void combine_u(const float* __restrict__ P,
                                                 const float* __restrict__ de_acc,
                                                 unsigned short* __restrict__ Ut) {
    const int PS = BATCH * DOUT * EE;
    int idx = (blockIdx.x * 256 + threadIdx.x) * 4;
    f32x4 s = *(const f32x4*)(P + idx);
    s += *(const f32x4*)(P + PS + idx);
    s += *(const f32x4*)(P + 2 * PS + idx);
    s += *(const f32x4*)(P + 3 * PS + idx);
    int b = idx >> 18, e = idx & (EE - 1);
    float4 de = *(const float4*)(de_acc + b * EE + e);
    ushort4 o = { f2bf(s.x / fmaxf(de.x, EPS)), f2bf(s.y / fmaxf(de.y, EPS)),
                  f2bf(s.z / fmaxf(de.z, EPS)), f2bf(s.w / fmaxf(de.w, EPS)) };
    *(ushort4*)(Ut + idx) = o;
}

// out[b][n][f] = rsqrt(max(dv,eps))[n] * sum_e Ut[f][e] Hb[n][e] + bias[f]
// (computed as C[i=f][j=n] so H_bf's native [n][e] layout is the B' operand)
__global__ __launch_bounds__(256) void mfma_hu(const unsigned short* __restrict__ Ut,
                                               const unsigned short* __restrict__ Hb,
                                               const float* __restrict__ dv_acc,
                                               const float* __restrict__ bias,
                                               float* __restrict__ out) {
    __shared__ short As[128 * 32], Bs[128 * 32];
    int f0 = blockIdx.x * 128, n0 = blockIdx.y * 128, b = blockIdx.z;
    f32x4 acc[4][4] = {};
    gemm_core<EE, EE>(Ut + ((size_t)b * DOUT + f0) * EE, Hb + ((size_t)b * NN + n0) * EE,
                      EE / 32, 0, acc, As, Bs);
    int lane = threadIdx.x & 63, wave = threadIdx.x >> 6;
    int wm = (wave >> 1) * 64, wn = (wave & 1) * 64;
    int rg = (lane >> 4) * 4, cl = lane & 15;
    float dvv[4];
#pragma unroll
    for (int j = 0; j < 4; ++j) {
        int n = n0 + wn + j * 16 + cl;
        dvv[j] = rsqrtf(fmaxf(dv_acc[b * NN + n], EPS));
    }
#pragma unroll
    for (int i = 0; i < 4; ++i) {
        int f = f0 + wm + i * 16 + rg;
        float4 bi = *(const float4*)(bias + f);
#pragma unroll
        for (int j = 0; j < 4; ++j) {
            int n = n0 + wn + j * 16 + cl;
            f32x4 a = acc[i][j];
            float4 o = { a.x * dvv[j] + bi.x, a.y * dvv[j] + bi.y,
                         a.z * dvv[j] + bi.z, a.w * dvv[j] + bi.w };
            *(float4*)(out + (((size_t)b * NN + n) << 8) + f) = o;
        }
    }
}

// ---------------- fp32 fallback path (round-1 proven; used if ws too small) ----------------

__global__ __launch_bounds__(256) void dv_kernel(const float* __restrict__ H, float* __restrict__ dv_is) {
    int row = blockIdx.x * 4 + (threadIdx.x >> 6);
    int lane = threadIdx.x & 63;
    const float4* p = (const float4*)(H + (size_t)row * EE);
    float s = 0.f;
#pragma unroll
    for (int j = 0; j < 4; ++j) { float4 v = p[j * 64 + lane]; s += v.x + v.y + v.z + v.w; }
#pragma unroll
    for (int off = 32; off; off >>= 1) s += __shfl_down(s, off);
    if (lane == 0) dv_is[row] = rsqrtf(fmaxf(s, EPS));
}
__global__ void zero_kernel(float* __restrict__ p, int n) {
    int i = blockIdx.x * 256 + threadIdx.x;
    if (i < n) p[i] = 0.f;
}
__global__ __launch_bounds__(256) void de_kernel(const float* __restrict__ H, float* __restrict__ de_acc) {
    int b = blockIdx.x >> 4, chunk = blockIdx.x & 15;
    int e = blockIdx.y * 256 + threadIdx.x;
    const float* p = H + ((size_t)b * NN + chunk * 256) * EE + e;
    float s = 0.f;
    for (int n = 0; n < 256; ++n) s += p[(size_t)n * EE];
    atomicAdd(&de_acc[b * EE + e], s);
}
__global__ void de_finalize(float* __restrict__ de) {
    int i = blockIdx.x * 256 + threadIdx.x;
    de[i] = 1.0f / fmaxf(de[i], EPS);
}
__global__ __launch_bounds__(256) void gemm_xw(const float* __restrict__ X, const float* __restrict__ W,
                                               const float* __restrict__ dv_is, float* __restrict__ T) {
    int b = blockIdx.z;
    int m0 = blockIdx.x * 64, f0 = blockIdx.y * 64;
    const float* A = X + (size_t)b * NN * DIN;
    __shared__ float As[16][68];
    __shared__ float Bs[16][68];
    int tid = threadIdx.x;
    int ar = tid >> 2, ac = (tid & 3) << 2;
    int br = tid >> 4, bc = (tid & 15) << 2;
    int r0 = (tid >> 4) << 2, c0 = (tid & 15) << 2;
    float acc[4][4] = {};
    for (int k0 = 0; k0 < DIN; k0 += 16) {
        float4 av = *(const float4*)&A[(size_t)(m0 + ar) * DIN + k0 + ac];
        float4 bv = *(const float4*)&W[(size_t)(k0 + br) * DOUT + f0 + bc];
        __syncthreads();
        As[ac + 0][ar] = av.x; As[ac + 1][ar] = av.y; As[ac + 2][ar] = av.z; As[ac + 3][ar] = av.w;
        *(float4*)&Bs[br][bc] = bv;
        __syncthreads();
#pragma unroll
        for (int k = 0; k < 16; ++k) {
            float4 a4 = *(const float4*)&As[k][r0];
            float4 b4 = *(const float4*)&Bs[k][c0];
            float a[4] = {a4.x, a4.y, a4.z, a4.w};
            float bb[4] = {b4.x, b4.y, b4.z, b4.w};
#pragma unroll
            for (int i = 0; i < 4; ++i)
#pragma unroll
                for (int j = 0; j < 4; ++j) acc[i][j] = fmaf(a[i], bb[j], acc[i][j]);
        }
    }
#pragma unroll
    for (int i = 0; i < 4; ++i) {
        float dv = dv_is[b * NN + m0 + r0 + i];
        float4 o = {dv * acc[i][0], dv * acc[i][1], dv * acc[i][2], dv * acc[i][3]};
        *(float4*)&T[((size_t)b * NN + m0 + r0 + i) * DOUT + f0 + c0] = o;
    }
}
__global__ __launch_bounds__(256) void gemm_ht(const float* __restrict__ H, const float* __restrict__ T,
                                               const float* __restrict__ de_inv, float* __restrict__ U) {
    int b = blockIdx.z;
    int e0 = blockIdx.x * 64, f0 = blockIdx.y * 64;
    const float* Hb = H + (size_t)b * NN * EE;
    const float* Tb = T + (size_t)b * NN * DOUT;
    __shared__ float As[16][68];
    __shared__ float Bs[16][68];
    int tid = threadIdx.x;
    int lr = tid >> 4, lc = (tid & 15) << 2;
    int r0 = (tid >> 4) << 2, c0 = (tid & 15) << 2;
    float acc[4][4] = {};
    for (int n0 = 0; n0 < NN; n0 += 16) {
        float4 av = *(const float4*)&Hb[(size_t)(n0 + lr) * EE + e0 + lc];
        float4 bv = *(const float4*)&Tb[(size_t)(n0 + lr) * DOUT + f0 + lc];
        __syncthreads();
        *(float4*)&As[lr][lc] = av;
        *(float4*)&Bs[lr][lc] = bv;
        __syncthreads();
#pragma unroll
        for (int k = 0; k < 16; ++k) {
            float4 a4 = *(const float4*)&As[k][r0];
            float4 b4 = *(const float4*)&Bs[k][c0];
            float a[4] = {a4.x, a4.y, a4.z, a4.w};
            float bb[4] = {b4.x, b4.y, b4.z, b4.w};
#pragma unroll
            for (int i = 0; i < 4; ++i)
#pragma unroll
                for (int j = 0; j < 4; ++j) acc[i][j] = fmaf(a[i], bb[j], acc[i][j]);
        }
    }
#pragma unroll
    for (int i = 0; i < 4; ++i) {
        float de = de_inv[b * EE + e0 + r0 + i];
        float4 o = {de * acc[i][0], de * acc[i][1], de * acc[i][2], de * acc[i][3]};
        *(float4*)&U[((size_t)b * EE + e0 + r0 + i) * DOUT + f0 + c0] = o;
    }
}
__global__ __launch_bounds__(256) void gemm_hu(const float* __restrict__ H, const float* __restrict__ U,
                                               const float* __restrict__ dv_is, const float* __restrict__ bias,
                                               float* __restrict__ out) {
    int b = blockIdx.z;
    int n0 = blockIdx.x * 64, f0 = blockIdx.y * 64;
    const float* Hb = H + (size_t)b * NN * EE;
    const float* Ub = U + (size_t)b * EE * DOUT;
    __shared__ float As[16][68];
    __shared__ float Bs[16][68];
    int tid = threadIdx.x;
    int ar = tid >> 2, ac = (tid & 3) << 2;
    int br = tid >> 4, bc = (tid & 15) << 2;
    int r0 = (tid >> 4) << 2, c0 = (tid & 15) << 2;
    float acc[4][4] = {};
    for (int k0 = 0; k0 < EE; k0 += 16) {
        float4 av = *(const float4*)&Hb[(size_t)(n0 + ar) * EE + k0 + ac];
        float4 bv = *(const float4*)&Ub[(size_t)(k0 + br) * DOUT + f0 + bc];
        __syncthreads();
        As[ac + 0][ar] = av.x; As[ac + 1][ar] = av.y; As[ac + 2][ar] = av.z; As[ac + 3][ar] = av.w;
        *(float4*)&Bs[br][bc] = bv;
        __syncthreads();
#pragma unroll
        for (int k = 0; k < 16; ++k) {
            float4 a4 = *(const float4*)&As[k][r0];
            float4 b4 = *(const float4*)&Bs[k][c0];
            float a[4] = {a4.x, a4.y, a4.z, a4.w};
            float bb[4] = {b4.x, b4.y, b4.z, b4.w};
#pragma unroll
            for (int i = 0; i < 4; ++i)
#pragma unroll
                for (int j = 0; j < 4; ++j) acc[i][j] = fmaf(a[i], bb[j], acc[i][j]);
        }
    }
    float4 bi = *(const float4*)&bias[f0 + c0];
#pragma unroll
    for (int i = 0; i < 4; ++i) {
        float dv = dv_is[b * NN + n0 + r0 + i];
        float4 o = {dv * acc[i][0] + bi.x, dv * acc[i][1] + bi.y, dv * acc[i][2] + bi.z, dv * acc[i][3] + bi.w};
        *(float4*)&out[((size_t)b * NN + n0 + r0 + i) * DOUT + f0 + c0] = o;
    }
}

extern "C" void kernel_launch(void* const* d_in, const int* in_sizes, int n_in,
                              void* d_out, int out_size, void* d_ws, size_t ws_size,
                              hipStream_t stream) {
    const float* x    = (const float*)d_in[0];   // [B,N,DIN]
    const float* H    = (const float*)d_in[1];   // [B,N,E]
    const float* W    = (const float*)d_in[2];   // [DIN,DOUT]
    const float* bias = (const float*)d_in[3];   // [DOUT]
    float* out = (float*)d_out;                  // [B,N,DOUT]

    // fast path workspace: dv(32768f) de(8192f) P(8Mf) | Wt(64Ki u16) Ut(2Mi u16) Hb(32Mi) Ht(32Mi)
    const size_t NEED = (size_t)(BATCH * NN + BATCH * EE + 4 * BATCH * DOUT * EE) * 4 +
                        (size_t)(DIN * DOUT + BATCH * DOUT * EE +
                                 (size_t)BATCH * NN * EE * 2) * 2;  // = 172,261,376 B

    if (ws_size >= NEED) {
        float* dv_acc = (float*)d_ws;
        float* de_acc = dv_acc + BATCH * NN;
        float* P      = de_acc + BATCH * EE;
        unsigned short* Wt = (unsigned short*)(P + (size_t)4 * BATCH * DOUT * EE);
        unsigned short* Ut = Wt + DIN * DOUT;
        unsigned short* Hb = Ut + (size_t)BATCH * DOUT * EE;
        unsigned short* Ht = Hb + (size_t)BATCH * NN * EE;
        // d_out doubles as scratch: X_bf in first half, Tt in second half
        unsigned short* Xb = (unsigned short*)d_out;
        unsigned short* Tt = Xb + (size_t)BATCH * NN * DOUT;

        hipMemsetAsync(dv_acc, 0, (size_t)(BATCH * NN + BATCH * EE) * sizeof(float), stream);
        prep_h<<<8192, 256, 0, stream>>>(H, Hb, Ht, dv_acc, de_acc);
        prep_xw<<<2064, 256, 0, stream>>>(x, W, Xb, Wt);
        mfma_xw<<<dim3(256, 2), 256, 0, stream>>>(Xb, Wt, dv_acc, Tt);
        mfma_ht<<<dim3(8, 2, 32), 256, 0, stream>>>(Ht, Tt, P);
        combine_u<<<2048, 256, 0, stream>>>(P, de_acc, Ut);
        mfma_hu<<<dim3(2, 32, 8), 256, 0, stream>>>(Ut, Hb, dv_acc, bias, out);
    } else {
        // fp32 fallback (round-1 path)
        float* ws = (float*)d_ws;
        float* dv_is = ws;
        float* de    = ws + BATCH * NN;
        float* U     = de + BATCH * EE;
        float* T = out;
        dv_kernel<<<BATCH * NN / 4, 256, 0, stream>>>(H, dv_is);
        zero_kernel<<<(BATCH * EE + 255) / 256, 256, 0, stream>>>(de, BATCH * EE);
        de_kernel<<<dim3(BATCH * 16, EE / 256), 256, 0, stream>>>(H, de);
        de_finalize<<<BATCH * EE / 256, 256, 0, stream>>>(de);
        gemm_xw<<<dim3(NN / 64, DOUT / 64, BATCH), 256, 0, stream>>>(x, W, dv_is, T);
        gemm_ht<<<dim3(EE / 64, DOUT / 64, BATCH), 256, 0, stream>>>(H, T, de, U);
        gemm_hu<<<dim3(NN / 64, DOUT / 64, BATCH), 256, 0, stream>>>(H, U, dv_is, bias, out);
    }
}